// Round 1
// baseline (65.340 us; speedup 1.0000x reference)
//
#include <hip/hip_runtime.h>
#include <hip/hip_bf16.h>

#define NUM_TOKENS 262144
#define NUM_EXPERTS 128
#define TOPK 8

__global__ __launch_bounds__(256) void select_topk_kernel(
    const float* __restrict__ logits, float* __restrict__ out)
{
    const int t = blockIdx.x * 256 + threadIdx.x;
    const float4* row = reinterpret_cast<const float4*>(logits + (size_t)t * NUM_EXPERTS);

    float val[TOPK];
    int   idx[TOPK];
#pragma unroll
    for (int k = 0; k < TOPK; ++k) { val[k] = -__builtin_inff(); idx[k] = 0; }

    // Branch-free stable sorted insert (value desc, index asc on ties).
    auto process4 = [&](float4 q, int base) {
        float vv[4] = {q.x, q.y, q.z, q.w};
#pragma unroll
        for (int j = 0; j < 4; ++j) {
            float v = vv[j];
            int   i = base + j;
            if (v > val[TOPK - 1]) {
#pragma unroll
                for (int k = TOPK - 1; k >= 1; --k) {
                    bool  mv = v > val[k - 1];
                    bool  here = v > val[k];
                    float vk = mv ? val[k - 1] : (here ? v : val[k]);
                    int   ik = mv ? idx[k - 1] : (here ? i : idx[k]);
                    val[k] = vk;
                    idx[k] = ik;
                }
                if (v > val[0]) { val[0] = v; idx[0] = i; }
            }
        }
    };

    // Stream the row with one-ahead prefetch; each lane's 4 consecutive
    // float4 loads cover a full 64B line back-to-back (no over-fetch).
    float4 cur = row[0];
#pragma unroll 4
    for (int c = 0; c < NUM_EXPERTS / 4 - 1; ++c) {
        float4 nxt = row[c + 1];
        process4(cur, c * 4);
        cur = nxt;
    }
    process4(cur, NUM_EXPERTS - 4);

    // Softmax over the selected 8 logits == renormalized top-k probs.
    float m = val[0];
    float e[TOPK];
    float Z = 0.0f;
#pragma unroll
    for (int k = 0; k < TOPK; ++k) { e[k] = __expf(val[k] - m); Z += e[k]; }
    float inv = 1.0f / Z;

    float4 id0 = make_float4((float)idx[0], (float)idx[1], (float)idx[2], (float)idx[3]);
    float4 id1 = make_float4((float)idx[4], (float)idx[5], (float)idx[6], (float)idx[7]);
    float4 w0  = make_float4(e[0] * inv, e[1] * inv, e[2] * inv, e[3] * inv);
    float4 w1  = make_float4(e[4] * inv, e[5] * inv, e[6] * inv, e[7] * inv);

    float4* outv = reinterpret_cast<float4*>(out);
    outv[(size_t)t * 2]     = id0;
    outv[(size_t)t * 2 + 1] = id1;
    float4* outw = reinterpret_cast<float4*>(out + (size_t)NUM_TOKENS * TOPK);
    outw[(size_t)t * 2]     = w0;
    outw[(size_t)t * 2 + 1] = w1;
}

extern "C" void kernel_launch(void* const* d_in, const int* in_sizes, int n_in,
                              void* d_out, int out_size, void* d_ws, size_t ws_size,
                              hipStream_t stream) {
    const float* logits = (const float*)d_in[0];
    float* out = (float*)d_out;
    select_topk_kernel<<<NUM_TOKENS / 256, 256, 0, stream>>>(logits, out);
}

// Round 2
// 42.707 us; speedup vs baseline: 1.5300x; 1.5300x over previous
//
#include <hip/hip_runtime.h>
#include <hip/hip_bf16.h>

#define NUM_TOKENS 262144
#define NUM_EXPERTS 128
#define TOPK 8

#define NEG_INF (-__builtin_inff())

// 8 lanes cooperate on one token. Each lane owns one 64B line (16 experts).
// Block = 256 threads = 4 waves = 32 tokens. Grid = NUM_TOKENS/32.
__global__ __launch_bounds__(256) void select_topk_kernel(
    const float* __restrict__ logits, float* __restrict__ out)
{
    const int lane = threadIdx.x & 63;
    const int wv   = threadIdx.x >> 6;
    const int g    = lane >> 3;   // token slot within wave (0..7)
    const int s    = lane & 7;    // sublane within token group (0..7)
    const int t    = blockIdx.x * 32 + wv * 8 + g;

    const float4* row =
        reinterpret_cast<const float4*>(logits + (size_t)t * NUM_EXPERTS + s * 16);
    float4 q0 = row[0];
    float4 q1 = row[1];
    float4 q2 = row[2];
    float4 q3 = row[3];

    // Local stable top-8 of this lane's 16 elements (value desc, index asc).
    float val[TOPK];
    int   idx[TOPK];
#pragma unroll
    for (int k = 0; k < TOPK; ++k) { val[k] = NEG_INF; idx[k] = 0; }

    auto ins4 = [&](float4 q, int base) {
        float vv[4] = {q.x, q.y, q.z, q.w};
#pragma unroll
        for (int j = 0; j < 4; ++j) {
            float v = vv[j];
            int   i = base + j;
            if (v > val[TOPK - 1]) {
#pragma unroll
                for (int k = TOPK - 1; k >= 1; --k) {
                    bool  mv   = v > val[k - 1];
                    bool  here = v > val[k];
                    val[k] = mv ? val[k - 1] : (here ? v : val[k]);
                    idx[k] = mv ? idx[k - 1] : (here ? i : idx[k]);
                }
                if (v > val[0]) { val[0] = v; idx[0] = i; }
            }
        }
    };
    const int base = s * 16;
    ins4(q0, base);
    ins4(q1, base + 4);
    ins4(q2, base + 8);
    ins4(q3, base + 12);

    // 8 rounds: argmax across the 8 sublanes (tie-break: min index, matching
    // jax.lax.top_k stability), owner pops its head. Sublane s keeps round-s
    // winner. xor masks 1/2/4 only flip bits 0-2 -> stay within the group.
    float my_v = 0.0f;
    int   my_i = 0;
    float m    = 0.0f;  // global max (round-0 winner), uniform in group
#pragma unroll
    for (int r = 0; r < TOPK; ++r) {
        float bv = val[0];
        int   bi = idx[0];
#pragma unroll
        for (int msk = 1; msk <= 4; msk <<= 1) {
            float ov = __shfl_xor(bv, msk);
            int   oi = __shfl_xor(bi, msk);
            bool take = (ov > bv) || (ov == bv && oi < bi);
            bv = take ? ov : bv;
            bi = take ? oi : bi;
        }
        if (r == 0) m = bv;
        if (s == r) { my_v = bv; my_i = bi; }
        if (r < TOPK - 1) {
            bool own = ((bi >> 4) == s);  // per-token expert indices unique
#pragma unroll
            for (int k = 0; k < TOPK - 1; ++k) {
                val[k] = own ? val[k + 1] : val[k];
                idx[k] = own ? idx[k + 1] : idx[k];
            }
            val[TOPK - 1] = own ? NEG_INF : val[TOPK - 1];
        }
    }

    // Softmax over the 8 selected logits == renormalized top-k probs.
    float e = __expf(my_v - m);
    float Z = e;
#pragma unroll
    for (int msk = 1; msk <= 4; msk <<= 1) Z += __shfl_xor(Z, msk);
    float w = e * (1.0f / Z);

    // Coalesced stores: lane index == g*8+s -> contiguous 64 floats per wave.
    out[(size_t)t * TOPK + s] = (float)my_i;
    out[(size_t)NUM_TOKENS * TOPK + (size_t)t * TOPK + s] = w;
}

extern "C" void kernel_launch(void* const* d_in, const int* in_sizes, int n_in,
                              void* d_out, int out_size, void* d_ws, size_t ws_size,
                              hipStream_t stream) {
    const float* logits = (const float*)d_in[0];
    float* out = (float*)d_out;
    select_topk_kernel<<<NUM_TOKENS / 32, 256, 0, stream>>>(logits, out);
}

// Round 3
// 42.699 us; speedup vs baseline: 1.5302x; 1.0002x over previous
//
#include <hip/hip_runtime.h>
#include <hip/hip_bf16.h>

#define NUM_TOKENS 262144
#define NUM_EXPERTS 128
#define TOPK 8

typedef unsigned long long u64;
typedef unsigned int u32;

// Compare-exchange: keep larger key in a, smaller in b. Keys are unique, so
// no stability concerns; compiles to v_cmp_lt_u64 + 4 v_cndmask.
__device__ __forceinline__ void ce(u64& a, u64& b) {
    bool sw = b > a;
    u64 hi = sw ? b : a;
    u64 lo = sw ? a : b;
    a = hi; b = lo;
}

// Batcher odd-even mergesort, 8 elements, descending (19 CEs).
__device__ __forceinline__ void sort8(u64 k[8]) {
    ce(k[0],k[1]); ce(k[2],k[3]); ce(k[4],k[5]); ce(k[6],k[7]);
    ce(k[0],k[2]); ce(k[1],k[3]); ce(k[4],k[6]); ce(k[5],k[7]);
    ce(k[1],k[2]); ce(k[5],k[6]);
    ce(k[0],k[4]); ce(k[1],k[5]); ce(k[2],k[6]); ce(k[3],k[7]);
    ce(k[2],k[4]); ce(k[3],k[5]);
    ce(k[1],k[2]); ce(k[3],k[4]); ce(k[5],k[6]);
}

// Bitonic merge of a bitonic 8-sequence -> sorted descending (12 CEs).
__device__ __forceinline__ void bmerge8(u64 k[8]) {
    ce(k[0],k[4]); ce(k[1],k[5]); ce(k[2],k[6]); ce(k[3],k[7]);
    ce(k[0],k[2]); ce(k[1],k[3]); ce(k[4],k[6]); ce(k[5],k[7]);
    ce(k[0],k[1]); ce(k[2],k[3]); ce(k[4],k[5]); ce(k[6],k[7]);
}

// Monotone fp32 -> u32 transform; key = (sortable << 32) | (127 - idx).
// Larger key == larger value, ties -> smaller expert index. Unique keys.
__device__ __forceinline__ u64 make_key(float v, u32 low) {
    u32 b = __float_as_uint(v);
    u32 hi = b ^ (0x80000000u | (u32)((int)b >> 31));
    return ((u64)hi << 32) | low;
}

// 4 lanes per token; each lane owns 32 contiguous experts (128B).
// Block = 256 threads = 64 tokens. Grid = NUM_TOKENS/64.
__global__ __launch_bounds__(256) void select_topk_kernel(
    const float* __restrict__ logits, float* __restrict__ out)
{
    const int tid = blockIdx.x * 256 + threadIdx.x;
    const int t = tid >> 2;
    const int s = tid & 3;

    const float4* p = reinterpret_cast<const float4*>(
        logits + (size_t)t * NUM_EXPERTS + s * 32);

    u64 A[8];
    float4 c0 = p[0], c1 = p[1];
#pragma unroll
    for (int g = 0; g < 4; ++g) {
        float4 n0, n1;
        if (g < 3) { n0 = p[2*g + 2]; n1 = p[2*g + 3]; }   // prefetch next group

        const u32 lowb = 127u - (u32)(s * 32 + g * 8);
        u64 kb[8];
        kb[0] = make_key(c0.x, lowb - 0);
        kb[1] = make_key(c0.y, lowb - 1);
        kb[2] = make_key(c0.z, lowb - 2);
        kb[3] = make_key(c0.w, lowb - 3);
        kb[4] = make_key(c1.x, lowb - 4);
        kb[5] = make_key(c1.y, lowb - 5);
        kb[6] = make_key(c1.z, lowb - 6);
        kb[7] = make_key(c1.w, lowb - 7);
        sort8(kb);

        if (g == 0) {
#pragma unroll
            for (int i = 0; i < 8; ++i) A[i] = kb[i];
        } else {
            // top-8 of (A ∪ kb): reverse+max gives a bitonic seq of the top set.
            u64 tt[8];
#pragma unroll
            for (int i = 0; i < 8; ++i) {
                u64 b = kb[7 - i];
                tt[i] = A[i] > b ? A[i] : b;
            }
            bmerge8(tt);
#pragma unroll
            for (int i = 0; i < 8; ++i) A[i] = tt[i];
        }
        if (g < 3) { c0 = n0; c1 = n1; }
    }

    // Cross-lane merge over the 4 sublanes (xor masks 1,2 stay in-group).
    // After both stages, all 4 sublanes hold the identical global sorted top-8.
#pragma unroll
    for (int d = 1; d <= 2; d <<= 1) {
        u64 B[8];
#pragma unroll
        for (int i = 0; i < 8; ++i) B[i] = __shfl_xor(A[7 - i], d);
#pragma unroll
        for (int i = 0; i < 8; ++i) A[i] = A[i] > B[i] ? A[i] : B[i];
        bmerge8(A);
    }

    // Decode values; softmax over the 8 selected logits == renormalized probs.
    float v[8], e[8];
#pragma unroll
    for (int k = 0; k < 8; ++k) {
        u32 hi = (u32)(A[k] >> 32);
        u32 b = hi ^ (0x80000000u | ~((u32)((int)hi >> 31)));
        v[k] = __uint_as_float(b);
    }
    const float mx = v[0];
    float Z = 0.0f;
#pragma unroll
    for (int k = 0; k < 8; ++k) { e[k] = __expf(v[k] - mx); Z += e[k]; }
    const float inv = 1.0f / Z;

    // Sublane s stores ranks 2s, 2s+1 (static cndmask tree, no scratch).
    const bool s1 = (s & 1) != 0, s2 = (s & 2) != 0;
    u32 lA = s2 ? (s1 ? (u32)A[6] : (u32)A[4]) : (s1 ? (u32)A[2] : (u32)A[0]);
    u32 lB = s2 ? (s1 ? (u32)A[7] : (u32)A[5]) : (s1 ? (u32)A[3] : (u32)A[1]);
    float eA = s2 ? (s1 ? e[6] : e[4]) : (s1 ? e[2] : e[0]);
    float eB = s2 ? (s1 ? e[7] : e[5]) : (s1 ? e[3] : e[1]);

    float2 sid = make_float2((float)(int)(127u - lA), (float)(int)(127u - lB));
    float2 sw  = make_float2(eA * inv, eB * inv);

    reinterpret_cast<float2*>(out)[(size_t)t * 4 + s] = sid;
    reinterpret_cast<float2*>(out + (size_t)NUM_TOKENS * TOPK)[(size_t)t * 4 + s] = sw;
}

extern "C" void kernel_launch(void* const* d_in, const int* in_sizes, int n_in,
                              void* d_out, int out_size, void* d_ws, size_t ws_size,
                              hipStream_t stream) {
    const float* logits = (const float*)d_in[0];
    float* out = (float*)d_out;
    select_topk_kernel<<<NUM_TOKENS / 64, 256, 0, stream>>>(logits, out);
}